// Round 3
// baseline (398.635 us; speedup 1.0000x reference)
//
#include <hip/hip_runtime.h>
#include <stdint.h>

#define S_LEN 2048
#define HID   3584
#define NH    28
#define NKV   4
#define HD    128
#define NQKV  4608   // 3584 + 512 + 512
#define GRP   7      // NH / NKV

typedef float  f32x4  __attribute__((ext_vector_type(4)));
typedef __bf16 bf16x8 __attribute__((ext_vector_type(8)));

#define GLOAD_LDS16(gp, lp) \
  __builtin_amdgcn_global_load_lds((const __attribute__((address_space(1))) void*)(gp), \
                                   (__attribute__((address_space(3))) void*)(lp), 16, 0, 0)

// ---------------- elementwise: f32 -> bf16 (x8 per thread) ----------------
__global__ void cvt_f32_bf16(const float* __restrict__ src, __bf16* __restrict__ dst, int n8) {
  int i = blockIdx.x * blockDim.x + threadIdx.x;
  if (i >= n8) return;
  const float4 a = *(const float4*)(src + (size_t)i * 8);
  const float4 b = *(const float4*)(src + (size_t)i * 8 + 4);
  bf16x8 o;
  o[0] = (__bf16)a.x; o[1] = (__bf16)a.y; o[2] = (__bf16)a.z; o[3] = (__bf16)a.w;
  o[4] = (__bf16)b.x; o[5] = (__bf16)b.y; o[6] = (__bf16)b.z; o[7] = (__bf16)b.w;
  *(bf16x8*)(dst + (size_t)i * 8) = o;
}

__global__ void concat_bias(const float* __restrict__ qb, const float* __restrict__ kb,
                            const float* __restrict__ vb, float* __restrict__ dst) {
  int i = blockIdx.x * blockDim.x + threadIdx.x;
  if (i >= NQKV) return;
  float v;
  if (i < HID) v = qb[i];
  else if (i < HID + 512) v = kb[i - HID];
  else v = vb[i - HID - 512];
  dst[i] = v;
}

// ---------------- GEMM: C[M][N] = A[M][K] * B[N][K]^T + bias ----------------
// bf16 in, OutT out. Tile 128x128, BK=64, 256 threads (4 waves, 2x2).
// Staging: global_load_lds width-16 with pre-swizzled global source so the
// linear LDS write lands in the XOR-swizzled layout the ds_read side expects.
#define BM 128
#define BN 128
#define BK 64

template <typename OutT>
__global__ __launch_bounds__(256) void gemm_bt(
    const __bf16* __restrict__ A, const __bf16* __restrict__ B,
    const float* __restrict__ bias, OutT* __restrict__ C,
    int M, int N, int K)
{
  __shared__ __bf16 As[BM * BK];
  __shared__ __bf16 Bs[BN * BK];

  const int t    = threadIdx.x;
  const int lane = t & 63;
  const int w    = t >> 6;       // wave 0..3
  const int wm   = w >> 1;
  const int wn   = w & 1;
  const int row0 = blockIdx.y * BM;
  const int col0 = blockIdx.x * BN;
  const int lq   = lane & 15;
  const int lg   = lane >> 4;

  // staging geometry: wave w owns rows [w*32, w*32+32) of the tile, as 4
  // segments of 8 rows; lane covers (row=l>>3, chunk=(l&7)^(l>>3 & 7)).
  const int sr  = lane >> 3;            // 0..7 row within segment
  const int sch = (lane & 7) ^ (sr & 7); // pre-swizzled source chunk
  const __bf16* aG = A + (size_t)(row0 + w * 32 + sr) * K + sch * 8;
  const __bf16* bG = B + (size_t)(col0 + w * 32 + sr) * K + sch * 8;
  __bf16* asW = As + w * 2048;   // w*32 rows * 64
  __bf16* bsW = Bs + w * 2048;

  f32x4 acc[4][4];
#pragma unroll
  for (int i = 0; i < 4; ++i)
#pragma unroll
    for (int j = 0; j < 4; ++j) { acc[i][j][0]=0.f; acc[i][j][1]=0.f; acc[i][j][2]=0.f; acc[i][j][3]=0.f; }

  for (int kt = 0; kt < K; kt += BK) {
    __syncthreads();
#pragma unroll
    for (int seg = 0; seg < 4; ++seg) {
      GLOAD_LDS16(aG + (size_t)seg * 8 * K + kt, asW + seg * 512);
      GLOAD_LDS16(bG + (size_t)seg * 8 * K + kt, bsW + seg * 512);
    }
    __syncthreads();

#pragma unroll
    for (int kk = 0; kk < 2; ++kk) {
      const int ch = kk * 4 + lg;
      bf16x8 af[4], bfr[4];
#pragma unroll
      for (int mf = 0; mf < 4; ++mf) {
        int r = wm * 64 + mf * 16 + lq;
        af[mf] = *(const bf16x8*)(As + r * BK + ((ch ^ (r & 7)) * 8));
      }
#pragma unroll
      for (int nf = 0; nf < 4; ++nf) {
        int r = wn * 64 + nf * 16 + lq;
        bfr[nf] = *(const bf16x8*)(Bs + r * BK + ((ch ^ (r & 7)) * 8));
      }
#pragma unroll
      for (int mf = 0; mf < 4; ++mf)
#pragma unroll
        for (int nf = 0; nf < 4; ++nf)
          acc[mf][nf] = __builtin_amdgcn_mfma_f32_16x16x32_bf16(af[mf], bfr[nf], acc[mf][nf], 0, 0, 0);
    }
  }

#pragma unroll
  for (int mf = 0; mf < 4; ++mf) {
#pragma unroll
    for (int nf = 0; nf < 4; ++nf) {
      int col = col0 + wn * 64 + nf * 16 + lq;
      float bv = bias ? bias[col] : 0.0f;
#pragma unroll
      for (int r = 0; r < 4; ++r) {
        int rowg = row0 + wm * 64 + mf * 16 + lg * 4 + r;
        C[(size_t)rowg * N + col] = (OutT)(acc[mf][nf][r] + bv);
      }
    }
  }
}

// ---------------- RoPE on Q/K (bf16 in/out, x8 per thread) ----------------
__global__ void rope_qk(const __bf16* __restrict__ qkv,
                        const float* __restrict__ cosb,
                        const float* __restrict__ sinb,
                        __bf16* __restrict__ Qo, __bf16* __restrict__ Ko)
{
  int i = blockIdx.x * blockDim.x + threadIdx.x;   // over S_LEN * (4096/8)
  if (i >= S_LEN * 512) return;
  const int s   = i >> 9;
  const int col = (i & 511) * 8;      // 0..4088, 8-aligned (sections are 8-aligned)
  const int d   = col & 127;
  const int axis = (d < 16) ? 0 : (d < 40) ? 1 : (d < 64) ? 2
                 : (d < 80) ? 0 : (d < 104) ? 1 : 2;

  const bf16x8 xv = *(const bf16x8*)(qkv + (size_t)s * NQKV + col);
  const int pcol  = col + ((d < 64) ? 64 : -64);
  const bf16x8 pv = *(const bf16x8*)(qkv + (size_t)s * NQKV + pcol);
  const float sgn = (d < 64) ? -1.0f : 1.0f;

  const float* cp = cosb + ((size_t)axis * S_LEN + s) * HD + d;
  const float* sp = sinb + ((size_t)axis * S_LEN + s) * HD + d;
  bf16x8 o;
#pragma unroll
  for (int j = 0; j < 8; ++j)
    o[j] = (__bf16)((float)xv[j] * cp[j] + sgn * (float)pv[j] * sp[j]);

  if (col < HID) {
    int h = col >> 7;
    *(bf16x8*)(Qo + ((size_t)h * S_LEN + s) * HD + d) = o;
  } else {
    int kh = (col - HID) >> 7;
    *(bf16x8*)(Ko + ((size_t)kh * S_LEN + s) * HD + d) = o;
  }
}

// ---------------- V transpose: qkv[s][4096+kh*128+d] -> Vt[kh][d][s] ----------------
// Block: 256 threads; tile 64(s) x 64(d) per (kh, s0, d0).
__global__ __launch_bounds__(256) void v_transpose(const __bf16* __restrict__ qkv,
                                                   __bf16* __restrict__ Vt)
{
  __shared__ __bf16 tile[64][72];   // +8 pad
  const int b   = blockIdx.x;       // NKV * 32 * 2
  const int kh  = b >> 6;
  const int s0  = ((b >> 1) & 31) * 64;
  const int d0  = (b & 1) * 64;
  const int t   = threadIdx.x;

#pragma unroll
  for (int p = 0; p < 2; ++p) {
    int sl = p * 32 + (t >> 3);
    int c  = t & 7;
    bf16x8 v = *(const bf16x8*)(qkv + (size_t)(s0 + sl) * NQKV + 4096 + kh * HD + d0 + c * 8);
#pragma unroll
    for (int j = 0; j < 8; ++j) tile[sl][c * 8 + j] = v[j];
  }
  __syncthreads();
#pragma unroll
  for (int p = 0; p < 2; ++p) {
    int idx = p * 256 + t;
    int dl  = idx >> 3;      // 0..63
    int sg  = idx & 7;       // 8-s group
    bf16x8 o;
#pragma unroll
    for (int j = 0; j < 8; ++j) o[j] = tile[sg * 8 + j][dl];
    *(bf16x8*)(Vt + ((size_t)kh * HD + d0 + dl) * S_LEN + s0 + sg * 8) = o;
  }
}

// ---------------- Flash attention (causal, GQA) ----------------
// Grid: (S/128, NH) with reversed qtile order. Block: 512 threads = 8 waves;
// wave w owns 16 q-rows; KV tiles of 64 shared block-wide.
__global__ __launch_bounds__(512) void attn_fwd(
    const __bf16* __restrict__ Q, const __bf16* __restrict__ K,
    const __bf16* __restrict__ Vt, __bf16* __restrict__ O)
{
  __shared__ __bf16 Ks[64 * HD];      // 64 k-rows x 128 d (swizzled 16B chunks)
  __shared__ __bf16 Vs[HD * 64];      // 128 d-rows x 64 k (swizzled)
  __shared__ __bf16 Ps[8][16 * 64];   // per-wave P tile (swizzled)

  const int t     = threadIdx.x;
  const int lane  = t & 63;
  const int w     = t >> 6;
  const int qtile = (gridDim.x - 1) - blockIdx.x;   // heavy tiles first
  const int h     = blockIdx.y;
  const int kvh   = h / GRP;
  const int q0    = qtile * 128 + w * 16;
  const int lq    = lane & 15;
  const int lg    = lane >> 4;

  bf16x8 qf[4];
  {
    const __bf16* qp = Q + ((size_t)h * S_LEN + q0 + lq) * HD + lg * 8;
#pragma unroll
    for (int dd = 0; dd < 4; ++dd) qf[dd] = *(const bf16x8*)(qp + dd * 32);
  }

  f32x4 of[8];
#pragma unroll
  for (int i = 0; i < 8; ++i) { of[i][0]=0.f; of[i][1]=0.f; of[i][2]=0.f; of[i][3]=0.f; }
  float m_run[4], l_run[4];
#pragma unroll
  for (int r = 0; r < 4; ++r) { m_run[r] = -1e30f; l_run[r] = 0.0f; }

  const float scale = 0.08838834764831845f;  // 1/sqrt(128)
  const int nkt = 2 * qtile + 2;             // 64-wide KV tiles covering q-range

  for (int kt = 0; kt < nkt; ++kt) {
    __syncthreads();
    {
      // K tile: 64 rows x 256B; 512 threads, 2 passes
      int krow = t >> 4, kch = t & 15;
#pragma unroll
      for (int p = 0; p < 2; ++p) {
        int rr = p * 32 + krow;
        uint4 v = *(const uint4*)(K + ((size_t)kvh * S_LEN + kt * 64 + rr) * HD + kch * 8);
        *(uint4*)(Ks + rr * HD + ((kch ^ (rr & 7)) * 8)) = v;
      }
      // V^T tile: 128 rows x 128B; 512 threads, 2 passes
      int vrow = t >> 3, vch = t & 7;
#pragma unroll
      for (int p = 0; p < 2; ++p) {
        int rr = p * 64 + vrow;
        uint4 v = *(const uint4*)(Vt + ((size_t)kvh * HD + rr) * S_LEN + kt * 64 + vch * 8);
        *(uint4*)(Vs + rr * 64 + ((vch ^ (rr & 7)) * 8)) = v;
      }
    }
    __syncthreads();

    const bool active = (kt * 64) <= (q0 + 15);   // wave-uniform
    if (active) {
      // S fragments: S[q][k], q=lg*4+r, k=kb*16+lq
      f32x4 sf[4];
      __builtin_amdgcn_s_setprio(1);
#pragma unroll
      for (int kb = 0; kb < 4; ++kb) {
        sf[kb][0]=0.f; sf[kb][1]=0.f; sf[kb][2]=0.f; sf[kb][3]=0.f;
#pragma unroll
        for (int dd = 0; dd < 4; ++dd) {
          int r  = kb * 16 + lq;
          int ch = dd * 4 + lg;
          bf16x8 kf = *(const bf16x8*)(Ks + r * HD + ((ch ^ (r & 7)) * 8));
          sf[kb] = __builtin_amdgcn_mfma_f32_16x16x32_bf16(qf[dd], kf, sf[kb], 0, 0, 0);
        }
      }
      __builtin_amdgcn_s_setprio(0);

      const bool diag = (kt * 64 + 63 > q0);
      float tmax[4];
#pragma unroll
      for (int r = 0; r < 4; ++r) tmax[r] = -1e30f;
#pragma unroll
      for (int kb = 0; kb < 4; ++kb) {
#pragma unroll
        for (int r = 0; r < 4; ++r) {
          float v = sf[kb][r] * scale;
          if (diag) {
            int kg = kt * 64 + kb * 16 + lq;
            int qg = q0 + lg * 4 + r;
            if (kg > qg) v = -1e30f;
          }
          sf[kb][r] = v;
          tmax[r] = fmaxf(tmax[r], v);
        }
      }
#pragma unroll
      for (int m = 8; m >= 1; m >>= 1)
#pragma unroll
        for (int r = 0; r < 4; ++r) tmax[r] = fmaxf(tmax[r], __shfl_xor(tmax[r], m, 16));

      float psum[4], escale[4];
#pragma unroll
      for (int r = 0; r < 4; ++r) {
        float mn = fmaxf(m_run[r], tmax[r]);
        escale[r] = __expf(m_run[r] - mn);
        m_run[r] = mn;
        psum[r] = 0.0f;
      }
#pragma unroll
      for (int kb = 0; kb < 4; ++kb) {
#pragma unroll
        for (int r = 0; r < 4; ++r) {
          float p = __expf(sf[kb][r] - m_run[r]);
          psum[r] += p;
          int prow = lg * 4 + r;
          int pcol = kb * 16 + lq;
          Ps[w][prow * 64 + (((pcol >> 3) ^ (prow & 7)) * 8) + (pcol & 7)] = (__bf16)p;
        }
      }
#pragma unroll
      for (int m = 8; m >= 1; m >>= 1)
#pragma unroll
        for (int r = 0; r < 4; ++r) psum[r] += __shfl_xor(psum[r], m, 16);
#pragma unroll
      for (int r = 0; r < 4; ++r) l_run[r] = l_run[r] * escale[r] + psum[r];
#pragma unroll
      for (int db = 0; db < 8; ++db)
#pragma unroll
        for (int r = 0; r < 4; ++r) of[db][r] *= escale[r];

      // PV: O[q][d] += P[q][k] V[k][d]
      __builtin_amdgcn_s_setprio(1);
#pragma unroll
      for (int kc = 0; kc < 2; ++kc) {
        int ch = kc * 4 + lg;
        bf16x8 pa = *(const bf16x8*)(&Ps[w][lq * 64 + ((ch ^ (lq & 7)) * 8)]);
#pragma unroll
        for (int db = 0; db < 8; ++db) {
          int vr = db * 16 + lq;
          bf16x8 vf = *(const bf16x8*)(Vs + vr * 64 + ((ch ^ (vr & 7)) * 8));
          of[db] = __builtin_amdgcn_mfma_f32_16x16x32_bf16(pa, vf, of[db], 0, 0, 0);
        }
      }
      __builtin_amdgcn_s_setprio(0);
    }
  }

#pragma unroll
  for (int db = 0; db < 8; ++db) {
#pragma unroll
    for (int r = 0; r < 4; ++r) {
      int s = q0 + lg * 4 + r;
      int d = db * 16 + lq;
      O[(size_t)s * HID + h * HD + d] = (__bf16)(of[db][r] / l_run[r]);
    }
  }
}

// ---------------- launch ----------------
extern "C" void kernel_launch(void* const* d_in, const int* in_sizes, int n_in,
                              void* d_out, int out_size, void* d_ws, size_t ws_size,
                              hipStream_t stream) {
  const float* hidden = (const float*)d_in[0];
  const float* cosb   = (const float*)d_in[1];
  const float* sinb   = (const float*)d_in[2];
  // d_in[3] attention_mask: exactly causal additive -> implemented in-kernel
  const float* q_w = (const float*)d_in[4];
  const float* q_b = (const float*)d_in[5];
  const float* k_w = (const float*)d_in[6];
  const float* k_b = (const float*)d_in[7];
  const float* v_w = (const float*)d_in[8];
  const float* v_b = (const float*)d_in[9];
  const float* o_w = (const float*)d_in[10];
  float* out = (float*)d_out;

  char* ws = (char*)d_ws;
  size_t off = 0;
  auto alloc = [&](size_t bytes) {
    off = (off + 255) & ~(size_t)255;
    void* p = ws + off;
    off += bytes;
    return p;
  };

  __bf16* hid_bf  = (__bf16*)alloc((size_t)S_LEN * HID * 2);
  __bf16* Wqkv    = (__bf16*)alloc((size_t)NQKV * HID * 2);
  float*  bias    = (float*) alloc((size_t)NQKV * 4);
  __bf16* qkv_bf  = (__bf16*)alloc((size_t)S_LEN * NQKV * 2);
  __bf16* Qb      = (__bf16*)alloc((size_t)NH * S_LEN * HD * 2);
  __bf16* Kb      = (__bf16*)alloc((size_t)NKV * S_LEN * HD * 2);
  __bf16* Vtb     = (__bf16*)alloc((size_t)NKV * HD * S_LEN * 2);
  __bf16* attn_o  = (__bf16*)alloc((size_t)S_LEN * HID * 2);
  __bf16* ow_bf   = (__bf16*)alloc((size_t)HID * HID * 2);

  const int TB = 256;
  auto cdiv = [](int a, int b) { return (a + b - 1) / b; };

  int n;
  n = S_LEN * HID;  cvt_f32_bf16<<<cdiv(n / 8, TB), TB, 0, stream>>>(hidden, hid_bf, n / 8);
  n = HID * HID;    cvt_f32_bf16<<<cdiv(n / 8, TB), TB, 0, stream>>>(q_w, Wqkv, n / 8);
  n = 512 * HID;    cvt_f32_bf16<<<cdiv(n / 8, TB), TB, 0, stream>>>(k_w, Wqkv + (size_t)HID * HID, n / 8);
  n = 512 * HID;    cvt_f32_bf16<<<cdiv(n / 8, TB), TB, 0, stream>>>(v_w, Wqkv + (size_t)(HID + 512) * HID, n / 8);
  n = HID * HID;    cvt_f32_bf16<<<cdiv(n / 8, TB), TB, 0, stream>>>(o_w, ow_bf, n / 8);
  concat_bias<<<cdiv(NQKV, TB), TB, 0, stream>>>(q_b, k_b, v_b, bias);

  // QKV projection (bf16 out, bias fused)
  {
    dim3 grid(NQKV / BN, S_LEN / BM);
    gemm_bt<__bf16><<<grid, TB, 0, stream>>>(hid_bf, Wqkv, bias, qkv_bf, S_LEN, NQKV, HID);
  }

  // RoPE (Q,K) + V transpose
  n = S_LEN * 512;
  rope_qk<<<cdiv(n, TB), TB, 0, stream>>>(qkv_bf, cosb, sinb, Qb, Kb);
  v_transpose<<<NKV * 32 * 2, TB, 0, stream>>>(qkv_bf, Vtb);

  // flash attention: 128 q-rows per block, 8 waves
  {
    dim3 grid(S_LEN / 128, NH);
    attn_fwd<<<grid, 512, 0, stream>>>(Qb, Kb, Vtb, attn_o);
  }

  // output projection (f32 out)
  {
    dim3 grid(HID / BN, S_LEN / BM);
    gemm_bt<float><<<grid, TB, 0, stream>>>(attn_o, ow_bf, nullptr, out, S_LEN, HID, HID);
  }
}

// Round 4
// 375.970 us; speedup vs baseline: 1.0603x; 1.0603x over previous
//
#include <hip/hip_runtime.h>
#include <stdint.h>

#define S_LEN 2048
#define HID   3584
#define NH    28
#define NKV   4
#define HD    128
#define NQKV  4608   // 3584 + 512 + 512
#define GRP   7      // NH / NKV

typedef float  f32x4  __attribute__((ext_vector_type(4)));
typedef __bf16 bf16x8 __attribute__((ext_vector_type(8)));

#define GLOAD_LDS16(gp, lp) \
  __builtin_amdgcn_global_load_lds((const __attribute__((address_space(1))) void*)(gp), \
                                   (__attribute__((address_space(3))) void*)(lp), 16, 0, 0)

// ---------------- elementwise: f32 -> bf16 (x8 per thread) ----------------
__global__ void cvt_f32_bf16(const float* __restrict__ src, __bf16* __restrict__ dst, int n8) {
  int i = blockIdx.x * blockDim.x + threadIdx.x;
  if (i >= n8) return;
  const float4 a = *(const float4*)(src + (size_t)i * 8);
  const float4 b = *(const float4*)(src + (size_t)i * 8 + 4);
  bf16x8 o;
  o[0] = (__bf16)a.x; o[1] = (__bf16)a.y; o[2] = (__bf16)a.z; o[3] = (__bf16)a.w;
  o[4] = (__bf16)b.x; o[5] = (__bf16)b.y; o[6] = (__bf16)b.z; o[7] = (__bf16)b.w;
  *(bf16x8*)(dst + (size_t)i * 8) = o;
}

__global__ void concat_bias(const float* __restrict__ qb, const float* __restrict__ kb,
                            const float* __restrict__ vb, float* __restrict__ dst) {
  int i = blockIdx.x * blockDim.x + threadIdx.x;
  if (i >= NQKV) return;
  float v;
  if (i < HID) v = qb[i];
  else if (i < HID + 512) v = kb[i - HID];
  else v = vb[i - HID - 512];
  dst[i] = v;
}

// ---------------- GEMM: C[M][N] = A[M][K] * B[N][K]^T + bias ----------------
#define BM 128
#define BN 128
#define BK 64

template <typename OutT>
__global__ __launch_bounds__(256) void gemm_bt(
    const __bf16* __restrict__ A, const __bf16* __restrict__ B,
    const float* __restrict__ bias, OutT* __restrict__ C,
    int M, int N, int K)
{
  __shared__ __bf16 As[BM * BK];
  __shared__ __bf16 Bs[BN * BK];

  const int t    = threadIdx.x;
  const int lane = t & 63;
  const int w    = t >> 6;       // wave 0..3
  const int wm   = w >> 1;
  const int wn   = w & 1;
  const int row0 = blockIdx.y * BM;
  const int col0 = blockIdx.x * BN;
  const int lq   = lane & 15;
  const int lg   = lane >> 4;

  const int sr  = lane >> 3;             // 0..7 row within segment
  const int sch = (lane & 7) ^ (sr & 7); // pre-swizzled source chunk
  const __bf16* aG = A + (size_t)(row0 + w * 32 + sr) * K + sch * 8;
  const __bf16* bG = B + (size_t)(col0 + w * 32 + sr) * K + sch * 8;
  __bf16* asW = As + w * 2048;
  __bf16* bsW = Bs + w * 2048;

  f32x4 acc[4][4];
#pragma unroll
  for (int i = 0; i < 4; ++i)
#pragma unroll
    for (int j = 0; j < 4; ++j) { acc[i][j][0]=0.f; acc[i][j][1]=0.f; acc[i][j][2]=0.f; acc[i][j][3]=0.f; }

  for (int kt = 0; kt < K; kt += BK) {
    __syncthreads();
#pragma unroll
    for (int seg = 0; seg < 4; ++seg) {
      GLOAD_LDS16(aG + (size_t)seg * 8 * K + kt, asW + seg * 512);
      GLOAD_LDS16(bG + (size_t)seg * 8 * K + kt, bsW + seg * 512);
    }
    __syncthreads();

#pragma unroll
    for (int kk = 0; kk < 2; ++kk) {
      const int ch = kk * 4 + lg;
      bf16x8 af[4], bfr[4];
#pragma unroll
      for (int mf = 0; mf < 4; ++mf) {
        int r = wm * 64 + mf * 16 + lq;
        af[mf] = *(const bf16x8*)(As + r * BK + ((ch ^ (r & 7)) * 8));
      }
#pragma unroll
      for (int nf = 0; nf < 4; ++nf) {
        int r = wn * 64 + nf * 16 + lq;
        bfr[nf] = *(const bf16x8*)(Bs + r * BK + ((ch ^ (r & 7)) * 8));
      }
#pragma unroll
      for (int mf = 0; mf < 4; ++mf)
#pragma unroll
        for (int nf = 0; nf < 4; ++nf)
          acc[mf][nf] = __builtin_amdgcn_mfma_f32_16x16x32_bf16(af[mf], bfr[nf], acc[mf][nf], 0, 0, 0);
    }
  }

#pragma unroll
  for (int mf = 0; mf < 4; ++mf) {
#pragma unroll
    for (int nf = 0; nf < 4; ++nf) {
      int col = col0 + wn * 64 + nf * 16 + lq;
      float bv = bias ? bias[col] : 0.0f;
#pragma unroll
      for (int r = 0; r < 4; ++r) {
        int rowg = row0 + wm * 64 + mf * 16 + lg * 4 + r;
        C[(size_t)rowg * N + col] = (OutT)(acc[mf][nf][r] + bv);
      }
    }
  }
}

// ---------------- RoPE on Q/K (bf16 in/out, x8 per thread) ----------------
__global__ void rope_qk(const __bf16* __restrict__ qkv,
                        const float* __restrict__ cosb,
                        const float* __restrict__ sinb,
                        __bf16* __restrict__ Qo, __bf16* __restrict__ Ko)
{
  int i = blockIdx.x * blockDim.x + threadIdx.x;
  if (i >= S_LEN * 512) return;
  const int s   = i >> 9;
  const int col = (i & 511) * 8;
  const int d   = col & 127;
  const int axis = (d < 16) ? 0 : (d < 40) ? 1 : (d < 64) ? 2
                 : (d < 80) ? 0 : (d < 104) ? 1 : 2;

  const bf16x8 xv = *(const bf16x8*)(qkv + (size_t)s * NQKV + col);
  const int pcol  = col + ((d < 64) ? 64 : -64);
  const bf16x8 pv = *(const bf16x8*)(qkv + (size_t)s * NQKV + pcol);
  const float sgn = (d < 64) ? -1.0f : 1.0f;

  const float* cp = cosb + ((size_t)axis * S_LEN + s) * HD + d;
  const float* sp = sinb + ((size_t)axis * S_LEN + s) * HD + d;
  bf16x8 o;
#pragma unroll
  for (int j = 0; j < 8; ++j)
    o[j] = (__bf16)((float)xv[j] * cp[j] + sgn * (float)pv[j] * sp[j]);

  if (col < HID) {
    int h = col >> 7;
    *(bf16x8*)(Qo + ((size_t)h * S_LEN + s) * HD + d) = o;
  } else {
    int kh = (col - HID) >> 7;
    *(bf16x8*)(Ko + ((size_t)kh * S_LEN + s) * HD + d) = o;
  }
}

// ---------------- V transpose ----------------
__global__ __launch_bounds__(256) void v_transpose(const __bf16* __restrict__ qkv,
                                                   __bf16* __restrict__ Vt)
{
  __shared__ __bf16 tile[64][72];
  const int b   = blockIdx.x;
  const int kh  = b >> 6;
  const int s0  = ((b >> 1) & 31) * 64;
  const int d0  = (b & 1) * 64;
  const int t   = threadIdx.x;

#pragma unroll
  for (int p = 0; p < 2; ++p) {
    int sl = p * 32 + (t >> 3);
    int c  = t & 7;
    bf16x8 v = *(const bf16x8*)(qkv + (size_t)(s0 + sl) * NQKV + 4096 + kh * HD + d0 + c * 8);
#pragma unroll
    for (int j = 0; j < 8; ++j) tile[sl][c * 8 + j] = v[j];
  }
  __syncthreads();
#pragma unroll
  for (int p = 0; p < 2; ++p) {
    int idx = p * 256 + t;
    int dl  = idx >> 3;
    int sg  = idx & 7;
    bf16x8 o;
#pragma unroll
    for (int j = 0; j < 8; ++j) o[j] = tile[sg * 8 + j][dl];
    *(bf16x8*)(Vt + ((size_t)kh * HD + d0 + dl) * S_LEN + s0 + sg * 8) = o;
  }
}

// ---------------- Flash attention (causal, GQA), 2-phase pipelined ----------------
// Grid: (S/64, NH), qtile reversed (heavy first). Block: 256 threads = 4 waves;
// wave w owns 16 q-rows. KV tiles of 64, double-buffered LDS staged via
// global_load_lds (pre-swizzled source), prefetch overlapped with compute,
// ONE barrier per KV iteration.
__global__ __launch_bounds__(256) void attn_fwd(
    const __bf16* __restrict__ Q, const __bf16* __restrict__ K,
    const __bf16* __restrict__ Vt, __bf16* __restrict__ O)
{
  __shared__ __bf16 Ks[2 * 64 * HD];   // dbuf: 64 k-rows x 128 d (swizzled)
  __shared__ __bf16 Vs[2 * HD * 64];   // dbuf: 128 d-rows x 64 k (swizzled)
  __shared__ __bf16 Ps[4][16 * 64];    // per-wave P tile (swizzled)

  const int t     = threadIdx.x;
  const int lane  = t & 63;
  const int w     = t >> 6;
  const int qtile = (gridDim.x - 1) - blockIdx.x;
  const int h     = blockIdx.y;
  const int kvh   = h / GRP;
  const int q0    = qtile * 64 + w * 16;
  const int lq    = lane & 15;
  const int lg    = lane >> 4;

  // ---- staging geometry (per wave: 4 issues K + 4 issues V, 1KB each) ----
  // K: issue j covers rows (w*4+j)*4 .. +4; lane: row +=lane>>4, chunk lane&15
  const int krow_in = (lane >> 4);           // 0..3
  const int kch     = lane & 15;
  // V: issue j covers rows (w*4+j)*8 .. +8; lane: row += lane>>3, chunk lane&7
  const int vrow_in = (lane >> 3);           // 0..7
  const int vch     = lane & 7;

  const __bf16* Kbase = K  + (size_t)kvh * S_LEN * HD;
  const __bf16* Vbase = Vt + (size_t)kvh * HD * S_LEN;

  bf16x8 qf[4];
  {
    const __bf16* qp = Q + ((size_t)h * S_LEN + q0 + lq) * HD + lg * 8;
#pragma unroll
    for (int dd = 0; dd < 4; ++dd) qf[dd] = *(const bf16x8*)(qp + dd * 32);
  }

  f32x4 of[8];
#pragma unroll
  for (int i = 0; i < 8; ++i) { of[i][0]=0.f; of[i][1]=0.f; of[i][2]=0.f; of[i][3]=0.f; }
  float m_run[4], l_run[4];
#pragma unroll
  for (int r = 0; r < 4; ++r) { m_run[r] = -1e30f; l_run[r] = 0.0f; }

  const float scale = 0.08838834764831845f;
  const int nkt = qtile + 1;

  // ---- STAGE macro: issue 8 global_load_lds for tile kt into buffer b ----
#define STAGE_KV(ktile, b)                                                          \
  {                                                                                 \
    _Pragma("unroll")                                                               \
    for (int j = 0; j < 4; ++j) {                                                   \
      int rr = (w * 4 + j) * 4 + krow_in;                                           \
      int sc = kch ^ (rr & 7);                                                      \
      GLOAD_LDS16(Kbase + (size_t)((ktile) * 64 + rr) * HD + sc * 8,                \
                  Ks + (b) * 8192 + (w * 4 + j) * 512);                             \
    }                                                                               \
    _Pragma("unroll")                                                               \
    for (int j = 0; j < 4; ++j) {                                                   \
      int rr = (w * 4 + j) * 8 + vrow_in;                                           \
      int sc = vch ^ (rr & 7);                                                      \
      GLOAD_LDS16(Vbase + (size_t)rr * S_LEN + (ktile) * 64 + sc * 8,               \
                  Vs + (b) * 8192 + (w * 4 + j) * 512);                             \
    }                                                                               \
  }

  STAGE_KV(0, 0);
  __syncthreads();   // drains vmcnt(0) before barrier

  int cur = 0;
  for (int kt = 0; kt < nkt; ++kt) {
    if (kt + 1 < nkt) STAGE_KV(kt + 1, cur ^ 1);

    const __bf16* KsC = Ks + cur * 8192;
    const __bf16* VsC = Vs + cur * 8192;

    // QK^T: S[q][k], q=lg*4+r, k=kb*16+lq
    f32x4 sf[4];
    __builtin_amdgcn_s_setprio(1);
#pragma unroll
    for (int kb = 0; kb < 4; ++kb) {
      sf[kb][0]=0.f; sf[kb][1]=0.f; sf[kb][2]=0.f; sf[kb][3]=0.f;
#pragma unroll
      for (int dd = 0; dd < 4; ++dd) {
        int r  = kb * 16 + lq;
        int ch = dd * 4 + lg;
        bf16x8 kf = *(const bf16x8*)(KsC + r * HD + ((ch ^ (r & 7)) * 8));
        sf[kb] = __builtin_amdgcn_mfma_f32_16x16x32_bf16(qf[dd], kf, sf[kb], 0, 0, 0);
      }
    }
    __builtin_amdgcn_s_setprio(0);

    const bool diag = (kt == qtile);
    float tmax[4];
#pragma unroll
    for (int r = 0; r < 4; ++r) tmax[r] = -1e30f;
#pragma unroll
    for (int kb = 0; kb < 4; ++kb) {
#pragma unroll
      for (int r = 0; r < 4; ++r) {
        float v = sf[kb][r] * scale;
        if (diag) {
          int kg = kt * 64 + kb * 16 + lq;
          int qg = q0 + lg * 4 + r;
          if (kg > qg) v = -1e30f;
        }
        sf[kb][r] = v;
        tmax[r] = fmaxf(tmax[r], v);
      }
    }
#pragma unroll
    for (int m = 8; m >= 1; m >>= 1)
#pragma unroll
      for (int r = 0; r < 4; ++r) tmax[r] = fmaxf(tmax[r], __shfl_xor(tmax[r], m, 16));

    float psum[4], escale[4];
#pragma unroll
    for (int r = 0; r < 4; ++r) {
      float mn = fmaxf(m_run[r], tmax[r]);
      escale[r] = __expf(m_run[r] - mn);
      m_run[r] = mn;
      psum[r] = 0.0f;
    }
#pragma unroll
    for (int kb = 0; kb < 4; ++kb) {
#pragma unroll
      for (int r = 0; r < 4; ++r) {
        float p = __expf(sf[kb][r] - m_run[r]);
        psum[r] += p;
        int prow = lg * 4 + r;
        int pcol = kb * 16 + lq;
        Ps[w][prow * 64 + (((pcol >> 3) ^ (prow & 7)) * 8) + (pcol & 7)] = (__bf16)p;
      }
    }
#pragma unroll
    for (int m = 8; m >= 1; m >>= 1)
#pragma unroll
      for (int r = 0; r < 4; ++r) psum[r] += __shfl_xor(psum[r], m, 16);
#pragma unroll
    for (int r = 0; r < 4; ++r) l_run[r] = l_run[r] * escale[r] + psum[r];
#pragma unroll
    for (int db = 0; db < 8; ++db)
#pragma unroll
      for (int r = 0; r < 4; ++r) of[db][r] *= escale[r];

    // PV
    __builtin_amdgcn_s_setprio(1);
#pragma unroll
    for (int kc = 0; kc < 2; ++kc) {
      int ch = kc * 4 + lg;
      bf16x8 pa = *(const bf16x8*)(&Ps[w][lq * 64 + ((ch ^ (lq & 7)) * 8)]);
#pragma unroll
      for (int db = 0; db < 8; ++db) {
        int vr = db * 16 + lq;
        bf16x8 vf = *(const bf16x8*)(VsC + vr * 64 + ((ch ^ (vr & 7)) * 8));
        of[db] = __builtin_amdgcn_mfma_f32_16x16x32_bf16(pa, vf, of[db], 0, 0, 0);
      }
    }
    __builtin_amdgcn_s_setprio(0);

    __syncthreads();   // drains prefetch vmcnt + protects Ps/buffers
    cur ^= 1;
  }
#undef STAGE_KV

#pragma unroll
  for (int db = 0; db < 8; ++db) {
#pragma unroll
    for (int r = 0; r < 4; ++r) {
      int s = q0 + lg * 4 + r;
      int d = db * 16 + lq;
      O[(size_t)s * HID + h * HD + d] = (__bf16)(of[db][r] / l_run[r]);
    }
  }
}

// ---------------- launch ----------------
extern "C" void kernel_launch(void* const* d_in, const int* in_sizes, int n_in,
                              void* d_out, int out_size, void* d_ws, size_t ws_size,
                              hipStream_t stream) {
  const float* hidden = (const float*)d_in[0];
  const float* cosb   = (const float*)d_in[1];
  const float* sinb   = (const float*)d_in[2];
  const float* q_w = (const float*)d_in[4];
  const float* q_b = (const float*)d_in[5];
  const float* k_w = (const float*)d_in[6];
  const float* k_b = (const float*)d_in[7];
  const float* v_w = (const float*)d_in[8];
  const float* v_b = (const float*)d_in[9];
  const float* o_w = (const float*)d_in[10];
  float* out = (float*)d_out;

  char* ws = (char*)d_ws;
  size_t off = 0;
  auto alloc = [&](size_t bytes) {
    off = (off + 255) & ~(size_t)255;
    void* p = ws + off;
    off += bytes;
    return p;
  };

  __bf16* hid_bf  = (__bf16*)alloc((size_t)S_LEN * HID * 2);
  __bf16* Wqkv    = (__bf16*)alloc((size_t)NQKV * HID * 2);
  float*  bias    = (float*) alloc((size_t)NQKV * 4);
  __bf16* qkv_bf  = (__bf16*)alloc((size_t)S_LEN * NQKV * 2);
  __bf16* Qb      = (__bf16*)alloc((size_t)NH * S_LEN * HD * 2);
  __bf16* Kb      = (__bf16*)alloc((size_t)NKV * S_LEN * HD * 2);
  __bf16* Vtb     = (__bf16*)alloc((size_t)NKV * HD * S_LEN * 2);
  __bf16* attn_o  = (__bf16*)alloc((size_t)S_LEN * HID * 2);
  __bf16* ow_bf   = (__bf16*)alloc((size_t)HID * HID * 2);

  const int TB = 256;
  auto cdiv = [](int a, int b) { return (a + b - 1) / b; };

  int n;
  n = S_LEN * HID;  cvt_f32_bf16<<<cdiv(n / 8, TB), TB, 0, stream>>>(hidden, hid_bf, n / 8);
  n = HID * HID;    cvt_f32_bf16<<<cdiv(n / 8, TB), TB, 0, stream>>>(q_w, Wqkv, n / 8);
  n = 512 * HID;    cvt_f32_bf16<<<cdiv(n / 8, TB), TB, 0, stream>>>(k_w, Wqkv + (size_t)HID * HID, n / 8);
  n = 512 * HID;    cvt_f32_bf16<<<cdiv(n / 8, TB), TB, 0, stream>>>(v_w, Wqkv + (size_t)(HID + 512) * HID, n / 8);
  n = HID * HID;    cvt_f32_bf16<<<cdiv(n / 8, TB), TB, 0, stream>>>(o_w, ow_bf, n / 8);
  concat_bias<<<cdiv(NQKV, TB), TB, 0, stream>>>(q_b, k_b, v_b, bias);

  // QKV projection (bf16 out, bias fused)
  {
    dim3 grid(NQKV / BN, S_LEN / BM);
    gemm_bt<__bf16><<<grid, TB, 0, stream>>>(hid_bf, Wqkv, bias, qkv_bf, S_LEN, NQKV, HID);
  }

  // RoPE (Q,K) + V transpose
  n = S_LEN * 512;
  rope_qk<<<cdiv(n, TB), TB, 0, stream>>>(qkv_bf, cosb, sinb, Qb, Kb);
  v_transpose<<<NKV * 32 * 2, TB, 0, stream>>>(qkv_bf, Vtb);

  // flash attention: 64 q-rows per block, 4 waves, 2-phase pipelined
  {
    dim3 grid(S_LEN / 64, NH);
    attn_fwd<<<grid, TB, 0, stream>>>(Qb, Kb, Vtb, attn_o);
  }

  // output projection (f32 out)
  {
    dim3 grid(HID / BN, S_LEN / BM);
    gemm_bt<float><<<grid, TB, 0, stream>>>(attn_o, ow_bf, nullptr, out, S_LEN, HID, HID);
  }
}